// Round 2
// baseline (305.646 us; speedup 1.0000x reference)
//
#include <hip/hip_runtime.h>
#include <hip/hip_bf16.h>

typedef __attribute__((ext_vector_type(8))) short bf16x8;
typedef __attribute__((ext_vector_type(4))) float f32x4;
typedef __hip_bfloat16 bf16;

#define BATCH 8
#define SEQ   2048
#define DMODEL 512
#define DHEAD 64
#define ROWS (BATCH * SEQ)

static __device__ inline short f2bf(float f) {
    union { __hip_bfloat16 h; short s; } u;
    u.h = __float2bfloat16(f);
    return u.s;
}

// ws layout (bf16 elements):
//  Q  [ROWS][64]          (2 MB)
//  K  [ROWS][64]          (2 MB)
//  Vt [BATCH][64][SEQ]    (2 MB)
//  Wt [3][64][512]        (196 KB)   order: wq, wk, wv  (flat [192][512])

__global__ __launch_bounds__(256) void transpose_w_kernel(
    const float* __restrict__ wq, const float* __restrict__ wk,
    const float* __restrict__ wv, bf16* __restrict__ wt)
{
    int idx = blockIdx.x * 256 + threadIdx.x;   // 0 .. 3*32768-1
    int s = idx >> 15;
    int r = idx & 32767;
    int n = r >> 9;          // 0..63
    int k = r & 511;         // 0..511
    const float* w = (s == 0) ? wq : ((s == 1) ? wk : wv);
    union { __hip_bfloat16 h; bf16 b; } u;
    u.h = __float2bfloat16(w[k * DHEAD + n]);
    wt[idx] = u.b;
}

// Fused QKV projection: 64 rows of X x all 192 output cols per block.
// grid (ROWS/64), block 512 (8 waves: wid&3 -> 16-row strip, wid>>2 -> col half).
__global__ __launch_bounds__(512) void proj_kernel(
    const float* __restrict__ x, const bf16* __restrict__ wt,
    bf16* __restrict__ Q, bf16* __restrict__ K, bf16* __restrict__ Vt)
{
    const int r0 = blockIdx.x * 64;

    __shared__ __align__(16) bf16 Xs[64][72];    // +8 pad: 2-way banks only
    __shared__ __align__(16) bf16 Ws[192][72];

    const int tid = threadIdx.x;
    const int lane = tid & 63;
    const int wid = tid >> 6;          // 0..7
    const int w4 = wid & 3;            // row strip
    const int whalf = wid >> 2;        // col half (c groups 0..5 / 6..11)
    const int l15 = lane & 15;
    const int quad = lane >> 4;

    f32x4 acc[6] = {};

    const int xrow = tid >> 3;         // 0..63
    const int xseg = tid & 7;          // 0..7 (8 floats each)

    for (int k0 = 0; k0 < DMODEL; k0 += 64) {
        // stage X (fp32 -> bf16)
        const float* xp = x + (size_t)(r0 + xrow) * DMODEL + k0 + xseg * 8;
        float4 xa = *(const float4*)(xp);
        float4 xb = *(const float4*)(xp + 4);
        bf16x8 xv;
        xv[0] = f2bf(xa.x); xv[1] = f2bf(xa.y); xv[2] = f2bf(xa.z); xv[3] = f2bf(xa.w);
        xv[4] = f2bf(xb.x); xv[5] = f2bf(xb.y); xv[6] = f2bf(xb.z); xv[7] = f2bf(xb.w);
        *(bf16x8*)(&Xs[xrow][xseg * 8]) = xv;

        // stage W^T (already bf16): 192 rows x 64 cols = 1536 segs of 8
#pragma unroll
        for (int s = 0; s < 3; ++s) {
            int sid = tid + s * 512;
            int wr = sid >> 3;
            int wc = (sid & 7) * 8;
            *(uint4*)(&Ws[wr][wc]) = *(const uint4*)(wt + (size_t)wr * DMODEL + k0 + wc);
        }
        __syncthreads();

        bf16x8 a0 = *(const bf16x8*)(&Xs[16 * w4 + l15][quad * 8]);
        bf16x8 a1 = *(const bf16x8*)(&Xs[16 * w4 + l15][32 + quad * 8]);
#pragma unroll
        for (int c = 0; c < 6; ++c) {
            int cg = whalf * 6 + c;
            bf16x8 b0 = *(const bf16x8*)(&Ws[16 * cg + l15][quad * 8]);
            bf16x8 b1 = *(const bf16x8*)(&Ws[16 * cg + l15][32 + quad * 8]);
            acc[c] = __builtin_amdgcn_mfma_f32_16x16x32_bf16(a0, b0, acc[c], 0, 0, 0);
            acc[c] = __builtin_amdgcn_mfma_f32_16x16x32_bf16(a1, b1, acc[c], 0, 0, 0);
        }
        __syncthreads();
    }

#pragma unroll
    for (int c = 0; c < 6; ++c) {
        int ng = 16 * (whalf * 6 + c) + l15;   // 0..191
        int sel = ng >> 6;
        int col = ng & 63;
#pragma unroll
        for (int r = 0; r < 4; ++r) {
            int row = r0 + 16 * w4 + quad * 4 + r;   // flat (b*SEQ + i)
            union { __hip_bfloat16 h; bf16 b; } u;
            u.h = __float2bfloat16(acc[c][r]);
            if (sel == 0)      Q[(size_t)row * DHEAD + col] = u.b;
            else if (sel == 1) K[(size_t)row * DHEAD + col] = u.b;
            else {
                int bb = row >> 11, j = row & (SEQ - 1);
                Vt[((size_t)bb * DHEAD + col) * SEQ + j] = u.b;
            }
        }
    }
}

// Flash attention: 32 Q-rows / block, 2 waves (16-row strip each), K-tile 64.
// grid (SEQ/32, BATCH), block 128.
__global__ __launch_bounds__(128) void flash_kernel(
    const bf16* __restrict__ Q, const bf16* __restrict__ K,
    const bf16* __restrict__ Vt, const int* __restrict__ mask,
    float* __restrict__ out)
{
    const int b = blockIdx.y;
    const int q0 = blockIdx.x * 32;
    const int tid = threadIdx.x;
    const int lane = tid & 63;
    const int wid = tid >> 6;      // 0..1
    const int l15 = lane & 15;
    const int quad = lane >> 4;

    __shared__ __align__(16) bf16 Ps[32][72];   // stride 144B: 2-way banks on b128

    const bf16* qp = Q + ((size_t)(b * SEQ + q0 + 16 * wid + l15)) * DHEAD + quad * 8;
    bf16x8 aQ0 = *(const bf16x8*)(qp);
    bf16x8 aQ1 = *(const bf16x8*)(qp + 32);

    f32x4 oacc[4] = {};
    float m_i[4], l_i[4];
#pragma unroll
    for (int r = 0; r < 4; ++r) { m_i[r] = -1e30f; l_i[r] = 0.f; }

    const size_t mrow0 = ((size_t)b * SEQ + (size_t)(q0 + 16 * wid + quad * 4)) * SEQ;

    for (int jt = 0; jt < SEQ / 64; ++jt) {
        const int j0 = jt * 64;

        // S = Q K^T (C layout: row q = quad*4+r, col j = 16c+l15)
        f32x4 sacc[4] = {};
#pragma unroll
        for (int c = 0; c < 4; ++c) {
            const bf16* kp = K + ((size_t)(b * SEQ + j0 + 16 * c + l15)) * DHEAD + quad * 8;
            bf16x8 b0 = *(const bf16x8*)(kp);
            bf16x8 b1 = *(const bf16x8*)(kp + 32);
            sacc[c] = __builtin_amdgcn_mfma_f32_16x16x32_bf16(aQ0, b0, sacc[c], 0, 0, 0);
            sacc[c] = __builtin_amdgcn_mfma_f32_16x16x32_bf16(aQ1, b1, sacc[c], 0, 0, 0);
        }

        // scale + mask (mask is int32 0/1)
        float sv[4][4];
#pragma unroll
        for (int c = 0; c < 4; ++c) {
#pragma unroll
            for (int r = 0; r < 4; ++r) {
                int mv = mask[mrow0 + (size_t)r * SEQ + (j0 + 16 * c + l15)];
                sv[c][r] = mv ? sacc[c][r] * 0.125f : -1e30f;
            }
        }

        // online softmax (row r lives on the 16 lanes of this quad)
#pragma unroll
        for (int r = 0; r < 4; ++r) {
            float rm = fmaxf(fmaxf(sv[0][r], sv[1][r]), fmaxf(sv[2][r], sv[3][r]));
            rm = fmaxf(rm, __shfl_xor(rm, 1));
            rm = fmaxf(rm, __shfl_xor(rm, 2));
            rm = fmaxf(rm, __shfl_xor(rm, 4));
            rm = fmaxf(rm, __shfl_xor(rm, 8));
            float mn = fmaxf(m_i[r], rm);
            float alpha = exp2f((m_i[r] - mn) * 1.44269504f);
            m_i[r] = mn;
            float rs = 0.f;
#pragma unroll
            for (int c = 0; c < 4; ++c) {
                float pv = exp2f((sv[c][r] - mn) * 1.44269504f);
                sv[c][r] = pv;
                rs += pv;
            }
            rs += __shfl_xor(rs, 1);
            rs += __shfl_xor(rs, 2);
            rs += __shfl_xor(rs, 4);
            rs += __shfl_xor(rs, 8);
            l_i[r] = l_i[r] * alpha + rs;
#pragma unroll
            for (int c = 0; c < 4; ++c) oacc[c][r] *= alpha;
        }

        // P: C-layout -> A-layout via LDS
#pragma unroll
        for (int c = 0; c < 4; ++c)
#pragma unroll
            for (int r = 0; r < 4; ++r) {
                union { __hip_bfloat16 h; bf16 b; } u;
                u.h = __float2bfloat16(sv[c][r]);
                Ps[16 * wid + quad * 4 + r][16 * c + l15] = u.b;
            }
        __syncthreads();

        bf16x8 aP0 = *(const bf16x8*)(&Ps[16 * wid + l15][quad * 8]);
        bf16x8 aP1 = *(const bf16x8*)(&Ps[16 * wid + l15][32 + quad * 8]);
#pragma unroll
        for (int c = 0; c < 4; ++c) {
            const bf16* vp = Vt + ((size_t)b * DHEAD + 16 * c + l15) * SEQ + j0 + quad * 8;
            bf16x8 v0 = *(const bf16x8*)(vp);
            bf16x8 v1 = *(const bf16x8*)(vp + 32);
            oacc[c] = __builtin_amdgcn_mfma_f32_16x16x32_bf16(aP0, v0, oacc[c], 0, 0, 0);
            oacc[c] = __builtin_amdgcn_mfma_f32_16x16x32_bf16(aP1, v1, oacc[c], 0, 0, 0);
        }
        __syncthreads();
    }

    // epilogue: out = oacc / l (fp32 output)
#pragma unroll
    for (int r = 0; r < 4; ++r) {
        float inv = 1.0f / l_i[r];
#pragma unroll
        for (int c = 0; c < 4; ++c) {
            int qr = q0 + 16 * wid + quad * 4 + r;
            out[((size_t)b * SEQ + qr) * DHEAD + 16 * c + l15] = oacc[c][r] * inv;
        }
    }
}

extern "C" void kernel_launch(void* const* d_in, const int* in_sizes, int n_in,
                              void* d_out, int out_size, void* d_ws, size_t ws_size,
                              hipStream_t stream)
{
    // setup_inputs order: mask, x_key_value, wk, wq, wv   (wk BEFORE wq!)
    const int*   mask = (const int*)d_in[0];
    const float* x    = (const float*)d_in[1];
    const float* wk   = (const float*)d_in[2];
    const float* wq   = (const float*)d_in[3];
    const float* wv   = (const float*)d_in[4];
    float* out = (float*)d_out;

    bf16* Qb = (bf16*)d_ws;
    bf16* Kb = Qb + (size_t)ROWS * DHEAD;
    bf16* Vt = Kb + (size_t)ROWS * DHEAD;
    bf16* Wt = Vt + (size_t)BATCH * DHEAD * SEQ;

    transpose_w_kernel<<<dim3(3 * 64 * DMODEL / 256), 256, 0, stream>>>(wq, wk, wv, Wt);
    proj_kernel<<<dim3(ROWS / 64), 512, 0, stream>>>(x, Wt, Qb, Kb, Vt);
    flash_kernel<<<dim3(SEQ / 32, BATCH), 128, 0, stream>>>(Qb, Kb, Vt, mask, out);
}

// Round 3
// 299.104 us; speedup vs baseline: 1.0219x; 1.0219x over previous
//
#include <hip/hip_runtime.h>
#include <hip/hip_bf16.h>

typedef __attribute__((ext_vector_type(8))) short bf16x8;
typedef __attribute__((ext_vector_type(4))) float f32x4;
typedef __hip_bfloat16 bf16;

#define BATCH 8
#define SEQ   2048
#define DMODEL 512
#define DHEAD 64
#define ROWS (BATCH * SEQ)
#define LOG2E 1.44269504f

static __device__ inline short f2bf(float f) {
    union { __hip_bfloat16 h; short s; } u;
    u.h = __float2bfloat16(f);
    return u.s;
}

// ---------------------------------------------------------------------------
// W transpose: w[512][64] fp32 -> wt[64][512] bf16, LDS-tiled, coalesced both
// sides. grid (3 sel x 8 k-tiles) = 24 blocks, block 256.
__global__ __launch_bounds__(256) void transpose_w_kernel(
    const float* __restrict__ wq, const float* __restrict__ wk,
    const float* __restrict__ wv, bf16* __restrict__ wt)
{
    const int s  = blockIdx.x / 8;       // 0:wq 1:wk 2:wv
    const int kt = blockIdx.x % 8;       // k-tile of 64
    const float* w = (s == 0) ? wq : ((s == 1) ? wk : wv);

    __shared__ float Ts[64][68];         // [k][n], +4 pad

    const int tid = threadIdx.x;
    // load: 64 k-rows x 64 n, float4 per thread, 4 rows per pass
    int nr = tid >> 4;                   // 0..15
    int n4 = (tid & 15) * 4;
#pragma unroll
    for (int p = 0; p < 4; ++p) {
        int k = 16 * p + nr;
        float4 v = *(const float4*)(w + (size_t)(kt * 64 + k) * DHEAD + n4);
        Ts[k][n4] = v.x; Ts[k][n4 + 1] = v.y; Ts[k][n4 + 2] = v.z; Ts[k][n4 + 3] = v.w;
    }
    __syncthreads();
    // store: wt[(s*64+n)*512 + kt*64 + kk], bf16x8 per thread, 2 chunks
#pragma unroll
    for (int p = 0; p < 2; ++p) {
        int cc = tid + p * 256;          // 0..511
        int n = cc >> 3;
        int kk = (cc & 7) * 8;
        bf16x8 o;
#pragma unroll
        for (int e = 0; e < 8; ++e) o[e] = f2bf(Ts[kk + e][n]);
        *(bf16x8*)(wt + (size_t)(s * 64 + n) * DMODEL + kt * 64 + kk) = o;
    }
}

// ---------------------------------------------------------------------------
// Fused QKV projection, no LDS / no barriers. grid ROWS/32 = 512 blocks,
// block 512 (8 waves): wave = (strip = wid&1 -> 16 rows, cq = wid>>1 -> 3 col
// groups of the 192 output cols). A from global x (fp32->bf16 in regs),
// B from L2-resident wt (bf16 direct).
__global__ __launch_bounds__(512) void proj_kernel(
    const float* __restrict__ x, const bf16* __restrict__ wt,
    bf16* __restrict__ Q, bf16* __restrict__ K, bf16* __restrict__ Vt)
{
    const int r0 = blockIdx.x * 32;
    const int tid = threadIdx.x;
    const int lane = tid & 63;
    const int wid = tid >> 6;          // 0..7
    const int strip = wid & 1;
    const int cq = wid >> 1;           // 0..3
    const int l15 = lane & 15;
    const int quad = lane >> 4;

    f32x4 acc[3] = {};

    const float* xp = x + (size_t)(r0 + 16 * strip + l15) * DMODEL;

    for (int k0 = 0; k0 < DMODEL; k0 += 64) {
        float4 xa = *(const float4*)(xp + k0 + quad * 8);
        float4 xb = *(const float4*)(xp + k0 + quad * 8 + 4);
        float4 xc = *(const float4*)(xp + k0 + 32 + quad * 8);
        float4 xd = *(const float4*)(xp + k0 + 32 + quad * 8 + 4);
        bf16x8 a0, a1;
        a0[0] = f2bf(xa.x); a0[1] = f2bf(xa.y); a0[2] = f2bf(xa.z); a0[3] = f2bf(xa.w);
        a0[4] = f2bf(xb.x); a0[5] = f2bf(xb.y); a0[6] = f2bf(xb.z); a0[7] = f2bf(xb.w);
        a1[0] = f2bf(xc.x); a1[1] = f2bf(xc.y); a1[2] = f2bf(xc.z); a1[3] = f2bf(xc.w);
        a1[4] = f2bf(xd.x); a1[5] = f2bf(xd.y); a1[6] = f2bf(xd.z); a1[7] = f2bf(xd.w);
#pragma unroll
        for (int g = 0; g < 3; ++g) {
            int n = 16 * (3 * cq + g) + l15;
            const bf16* wp = wt + (size_t)n * DMODEL + k0 + quad * 8;
            bf16x8 b0 = *(const bf16x8*)(wp);
            bf16x8 b1 = *(const bf16x8*)(wp + 32);
            acc[g] = __builtin_amdgcn_mfma_f32_16x16x32_bf16(a0, b0, acc[g], 0, 0, 0);
            acc[g] = __builtin_amdgcn_mfma_f32_16x16x32_bf16(a1, b1, acc[g], 0, 0, 0);
        }
    }

#pragma unroll
    for (int g = 0; g < 3; ++g) {
        int ng = 16 * (3 * cq + g) + l15;   // 0..191
        int sel = ng >> 6;
        int col = ng & 63;
#pragma unroll
        for (int r = 0; r < 4; ++r) {
            int row = r0 + 16 * strip + quad * 4 + r;   // flat (b*SEQ + i)
            union { __hip_bfloat16 h; bf16 b; } u;
            u.h = __float2bfloat16(acc[g][r]);
            if (sel == 0)      Q[(size_t)row * DHEAD + col] = u.b;
            else if (sel == 1) K[(size_t)row * DHEAD + col] = u.b;
            else {
                int bb = row >> 11, j = row & (SEQ - 1);
                Vt[((size_t)bb * DHEAD + col) * SEQ + j] = u.b;
            }
        }
    }
}

// ---------------------------------------------------------------------------
// Flash attention with 4-way j-split. grid (SEQ/16, BATCH) = 1024 blocks,
// block 256 (4 waves). All 4 waves share the block's 16 Q-rows; wave w owns
// j in [w*512, w*512+512). Zero barriers in the K-loop (Ps is wave-private);
// one barrier before the final combine.
__global__ __launch_bounds__(256) void flash_kernel(
    const bf16* __restrict__ Q, const bf16* __restrict__ K,
    const bf16* __restrict__ Vt, const int* __restrict__ mask,
    float* __restrict__ out)
{
    const int b = blockIdx.y;
    const int q0 = blockIdx.x * 16;
    const int tid = threadIdx.x;
    const int lane = tid & 63;
    const int wid = tid >> 6;      // 0..3 = j-split index
    const int l15 = lane & 15;
    const int quad = lane >> 4;

    __shared__ __align__(16) bf16 Ps[4][16][72];    // wave-private P tiles
    __shared__ float Om[4][16][64];                 // partial O per wave
    __shared__ float Mw[4][16];                     // partial m per wave
    __shared__ float Lw[4][16];                     // partial l per wave

    const bf16* qp = Q + ((size_t)(b * SEQ + q0 + l15)) * DHEAD + quad * 8;
    bf16x8 aQ0 = *(const bf16x8*)(qp);
    bf16x8 aQ1 = *(const bf16x8*)(qp + 32);

    f32x4 oacc[4] = {};
    float m_i[4], l_i[4];
#pragma unroll
    for (int r = 0; r < 4; ++r) { m_i[r] = -1e30f; l_i[r] = 0.f; }

    const int* mp = mask + ((size_t)(b * SEQ + q0 + quad * 4)) * SEQ;
    const int jbase = wid * (SEQ / 4);

    for (int jt = 0; jt < SEQ / 4; jt += 64) {
        const int j0 = jbase + jt;

        // S = Q K^T (C layout: row q = quad*4+r, col j = 16c+l15)
        f32x4 sacc[4] = {};
#pragma unroll
        for (int c = 0; c < 4; ++c) {
            const bf16* kp = K + ((size_t)(b * SEQ + j0 + 16 * c + l15)) * DHEAD + quad * 8;
            bf16x8 b0 = *(const bf16x8*)(kp);
            bf16x8 b1 = *(const bf16x8*)(kp + 32);
            sacc[c] = __builtin_amdgcn_mfma_f32_16x16x32_bf16(aQ0, b0, sacc[c], 0, 0, 0);
            sacc[c] = __builtin_amdgcn_mfma_f32_16x16x32_bf16(aQ1, b1, sacc[c], 0, 0, 0);
        }

        // scale + mask (in place, sacc becomes masked scaled scores)
#pragma unroll
        for (int c = 0; c < 4; ++c) {
#pragma unroll
            for (int r = 0; r < 4; ++r) {
                int mv = mp[(size_t)r * SEQ + (j0 + 16 * c + l15)];
                sacc[c][r] = mv ? sacc[c][r] * 0.125f : -1e30f;
            }
        }

        // online softmax (row r lives on the 16 lanes of this quad)
#pragma unroll
        for (int r = 0; r < 4; ++r) {
            float rm = fmaxf(fmaxf(sacc[0][r], sacc[1][r]), fmaxf(sacc[2][r], sacc[3][r]));
            rm = fmaxf(rm, __shfl_xor(rm, 1));
            rm = fmaxf(rm, __shfl_xor(rm, 2));
            rm = fmaxf(rm, __shfl_xor(rm, 4));
            rm = fmaxf(rm, __shfl_xor(rm, 8));
            float mn = fmaxf(m_i[r], rm);
            float alpha = exp2f((m_i[r] - mn) * LOG2E);
            m_i[r] = mn;
            float rs = 0.f;
#pragma unroll
            for (int c = 0; c < 4; ++c) {
                float pv = exp2f((sacc[c][r] - mn) * LOG2E);
                sacc[c][r] = pv;
                rs += pv;
            }
            rs += __shfl_xor(rs, 1);
            rs += __shfl_xor(rs, 2);
            rs += __shfl_xor(rs, 4);
            rs += __shfl_xor(rs, 8);
            l_i[r] = l_i[r] * alpha + rs;
#pragma unroll
            for (int c = 0; c < 4; ++c) oacc[c][r] *= alpha;
        }

        // P: C-layout -> A-layout via wave-private LDS (no barrier needed)
#pragma unroll
        for (int c = 0; c < 4; ++c)
#pragma unroll
            for (int r = 0; r < 4; ++r) {
                union { __hip_bfloat16 h; bf16 b; } u;
                u.h = __float2bfloat16(sacc[c][r]);
                Ps[wid][quad * 4 + r][16 * c + l15] = u.b;
            }

        bf16x8 aP0 = *(const bf16x8*)(&Ps[wid][l15][quad * 8]);
        bf16x8 aP1 = *(const bf16x8*)(&Ps[wid][l15][32 + quad * 8]);
#pragma unroll
        for (int c = 0; c < 4; ++c) {
            const bf16* vp = Vt + ((size_t)b * DHEAD + 16 * c + l15) * SEQ + j0 + quad * 8;
            bf16x8 v0 = *(const bf16x8*)(vp);
            bf16x8 v1 = *(const bf16x8*)(vp + 32);
            oacc[c] = __builtin_amdgcn_mfma_f32_16x16x32_bf16(aP0, v0, oacc[c], 0, 0, 0);
            oacc[c] = __builtin_amdgcn_mfma_f32_16x16x32_bf16(aP1, v1, oacc[c], 0, 0, 0);
        }
    }

    // stash partials
#pragma unroll
    for (int c = 0; c < 4; ++c)
#pragma unroll
        for (int r = 0; r < 4; ++r)
            Om[wid][quad * 4 + r][16 * c + l15] = oacc[c][r];
    if (l15 == 0) {
#pragma unroll
        for (int r = 0; r < 4; ++r) {
            Mw[wid][quad * 4 + r] = m_i[r];
            Lw[wid][quad * 4 + r] = l_i[r];
        }
    }
    __syncthreads();

    // combine: 256 threads, 4 output floats each (16 rows x 64 cols)
    {
        int row = tid >> 4;
        int c0 = (tid & 15) * 4;
        float M = fmaxf(fmaxf(Mw[0][row], Mw[1][row]), fmaxf(Mw[2][row], Mw[3][row]));
        float sc0 = exp2f((Mw[0][row] - M) * LOG2E);
        float sc1 = exp2f((Mw[1][row] - M) * LOG2E);
        float sc2 = exp2f((Mw[2][row] - M) * LOG2E);
        float sc3 = exp2f((Mw[3][row] - M) * LOG2E);
        float L = Lw[0][row] * sc0 + Lw[1][row] * sc1 + Lw[2][row] * sc2 + Lw[3][row] * sc3;
        float invL = 1.0f / L;
        float4 o;
        float* op = (float*)&o;
#pragma unroll
        for (int e = 0; e < 4; ++e) {
            op[e] = (Om[0][row][c0 + e] * sc0 + Om[1][row][c0 + e] * sc1 +
                     Om[2][row][c0 + e] * sc2 + Om[3][row][c0 + e] * sc3) * invL;
        }
        *(float4*)(out + ((size_t)(b * SEQ + q0 + row)) * DHEAD + c0) = o;
    }
}

extern "C" void kernel_launch(void* const* d_in, const int* in_sizes, int n_in,
                              void* d_out, int out_size, void* d_ws, size_t ws_size,
                              hipStream_t stream)
{
    // setup_inputs order: mask, x_key_value, wk, wq, wv   (wk BEFORE wq!)
    const int*   mask = (const int*)d_in[0];
    const float* x    = (const float*)d_in[1];
    const float* wk   = (const float*)d_in[2];
    const float* wq   = (const float*)d_in[3];
    const float* wv   = (const float*)d_in[4];
    float* out = (float*)d_out;

    bf16* Qb = (bf16*)d_ws;
    bf16* Kb = Qb + (size_t)ROWS * DHEAD;
    bf16* Vt = Kb + (size_t)ROWS * DHEAD;
    bf16* Wt = Vt + (size_t)BATCH * DHEAD * SEQ;

    transpose_w_kernel<<<dim3(24), 256, 0, stream>>>(wq, wk, wv, Wt);
    proj_kernel<<<dim3(ROWS / 32), 512, 0, stream>>>(x, Wt, Qb, Kb, Vt);
    flash_kernel<<<dim3(SEQ / 16, BATCH), 256, 0, stream>>>(Qb, Kb, Vt, mask, out);
}